// Round 1
// baseline (545.174 us; speedup 1.0000x reference)
//
#include <hip/hip_runtime.h>

// Problem constants (fixed by setup_inputs)
#define TB 16       // batch
#define TH 64       // height
#define TW 64       // width
#define TC 512      // channels
#define NHEADS 16
#define HD 32       // head dim
#define WS 8        // window size
#define SS 4        // shift size
#define NTOK 64     // tokens per window = WS*WS
#define NWH 8       // windows per spatial dim
#define LDK 36      // padded LDS row stride in floats (36*4=144 B, 16B-aligned)

__global__ __launch_bounds__(64)
void swin_attn_kernel(const float* __restrict__ q,
                      const float* __restrict__ k,
                      const float* __restrict__ v,
                      const float* __restrict__ bias_table,
                      float* __restrict__ out)
{
    __shared__ float Ks[NTOK * LDK];
    __shared__ float Vs[NTOK * LDK];
    __shared__ float Bs[225];   // (2*WS-1)^2 bias entries for this head

    const int blk  = blockIdx.x;          // 0 .. 16383
    const int head = blk & (NHEADS - 1);
    const int win  = (blk >> 4) & 63;
    const int b    = blk >> 10;
    const int wh   = win >> 3;
    const int ww   = win & 7;

    const int lane = threadIdx.x;         // 0..63 : query row index == staged K/V row
    const int ih = lane >> 3;
    const int iw = lane & 7;

    // Stage this head's bias column: Bs[idx] = bias_table[idx][head]
    for (int t = lane; t < 225; t += 64)
        Bs[t] = bias_table[t * NHEADS + head];

    // Global (unshifted) coords of this lane's token; cyclic shift is an index remap.
    const int gh = (wh * WS + ih + SS) & (TH - 1);
    const int gw = (ww * WS + iw + SS) & (TW - 1);
    const size_t rowbase = (((size_t)b * TH + gh) * TW + gw) * (size_t)TC
                         + (size_t)head * HD;

    // Stage K and V row `lane` into LDS (8 x float4 each)
    {
        const float4* krow = (const float4*)(k + rowbase);
        const float4* vrow = (const float4*)(v + rowbase);
        float4* kd = (float4*)&Ks[lane * LDK];
        float4* vd = (float4*)&Vs[lane * LDK];
        #pragma unroll
        for (int t = 0; t < 8; ++t) {
            kd[t] = krow[t];
            vd[t] = vrow[t];
        }
    }

    // Q row -> registers, pre-scaled by 1/sqrt(hd)
    float4 qv[8];
    {
        const float4* qrow = (const float4*)(q + rowbase);
        const float scale = 0.17677669529663687f;  // 32^-0.5
        #pragma unroll
        for (int t = 0; t < 8; ++t) {
            float4 x = qrow[t];
            x.x *= scale; x.y *= scale; x.z *= scale; x.w *= scale;
            qv[t] = x;
        }
    }

    // Shift-mask region label for this lane's row (shifted-image coordinates)
    const bool eh = (wh == NWH - 1);
    const bool ew = (ww == NWH - 1);
    const int ci = 3 * (eh ? (ih < (WS - SS) ? 1 : 2) : 0)
                 +     (ew ? (iw < (WS - SS) ? 1 : 2) : 0);

    __syncthreads();

    float4 acc[8];
    #pragma unroll
    for (int t = 0; t < 8; ++t) acc[t] = make_float4(0.f, 0.f, 0.f, 0.f);
    float l = 0.f;

    #pragma unroll 8
    for (int j = 0; j < NTOK; ++j) {
        const float4* kr = (const float4*)&Ks[j * LDK];
        // dot(q_i, k_j) with 4 partial sums for ILP
        float p0 = 0.f, p1 = 0.f, p2 = 0.f, p3 = 0.f;
        #pragma unroll
        for (int t = 0; t < 8; ++t) {
            float4 kk = kr[t];
            p0 = fmaf(kk.x, qv[t].x, p0);
            p1 = fmaf(kk.y, qv[t].y, p1);
            p2 = fmaf(kk.z, qv[t].z, p2);
            p3 = fmaf(kk.w, qv[t].w, p3);
        }
        float s = (p0 + p1) + (p2 + p3);

        const int jh = j >> 3, jw = j & 7;
        s += Bs[(ih - jh + 7) * 15 + (iw - jw + 7)];

        const int cj = 3 * (eh ? (jh < (WS - SS) ? 1 : 2) : 0)
                     +     (ew ? (jw < (WS - SS) ? 1 : 2) : 0);
        // masked entries get -100 in the reference -> contribution <= e^-40 of row mass;
        // selecting p = 0 is within tolerance and avoids the extreme exp.
        const float p = (ci == cj) ? __expf(s) : 0.f;
        l += p;

        const float4* vr = (const float4*)&Vs[j * LDK];
        #pragma unroll
        for (int t = 0; t < 8; ++t) {
            float4 vv = vr[t];
            acc[t].x = fmaf(p, vv.x, acc[t].x);
            acc[t].y = fmaf(p, vv.y, acc[t].y);
            acc[t].z = fmaf(p, vv.z, acc[t].z);
            acc[t].w = fmaf(p, vv.w, acc[t].w);
        }
    }

    // Normalize and store (window-reverse + reverse shift == same index remap)
    const float rl = 1.0f / l;
    float4* orow = (float4*)(out + rowbase);
    #pragma unroll
    for (int t = 0; t < 8; ++t) {
        float4 a = acc[t];
        a.x *= rl; a.y *= rl; a.z *= rl; a.w *= rl;
        orow[t] = a;
    }
}

extern "C" void kernel_launch(void* const* d_in, const int* in_sizes, int n_in,
                              void* d_out, int out_size, void* d_ws, size_t ws_size,
                              hipStream_t stream) {
    const float* q  = (const float*)d_in[0];
    const float* k  = (const float*)d_in[1];
    const float* v  = (const float*)d_in[2];
    const float* bt = (const float*)d_in[3];
    float* out = (float*)d_out;

    // 16 batches * 64 windows * 16 heads = 16384 blocks, 1 wave each
    dim3 grid(TB * 64 * NHEADS);
    dim3 block(64);
    swin_attn_kernel<<<grid, block, 0, stream>>>(q, k, v, bt, out);
}

// Round 2
// 437.704 us; speedup vs baseline: 1.2455x; 1.2455x over previous
//
#include <hip/hip_runtime.h>

// Problem constants (fixed by setup_inputs)
#define TB 16
#define NHEADS 16
#define HD 32
#define WS 8
#define SS 4

typedef __attribute__((ext_vector_type(8))) __bf16 bf16x8;
typedef __attribute__((ext_vector_type(4))) float f32x4;

__device__ __forceinline__ unsigned short f2bf(float f) {
    unsigned u = __float_as_uint(f);
    u += 0x7fff + ((u >> 16) & 1);   // round-to-nearest-even
    return (unsigned short)(u >> 16);
}
__device__ __forceinline__ unsigned pk2(float a, float b) {
    return (unsigned)f2bf(a) | ((unsigned)f2bf(b) << 16);
}
__device__ __forceinline__ float bf2f(unsigned short h) {
    return __uint_as_float(((unsigned)h) << 16);
}

// LDS layout (bytes):
//   [0,      5120)  Qs bf16 [64][40]  stride 80  -- overlaid by P after QK^T
//   [5120,  10240)  Ks bf16 [64][40]  stride 80
//   [0,      9216)  P  bf16 [64][72]  stride 144 (overlays Qs+Ks)
//   [10240, 14848)  Vt bf16 [32][72]  stride 144 (V transposed: [chan][token])
//   [14848, 23552)  St bf16 [64][68]  stride 136 (S transposed: St[j][i])
//   [23552, 24452)  Bs f32  [225]
#define OFF_Q 0
#define OFF_K 5120
#define OFF_P 0
#define OFF_V 10240
#define OFF_S 14848
#define OFF_B 23552

__global__ __launch_bounds__(64, 2)
void swin_attn_mfma(const float* __restrict__ q,
                    const float* __restrict__ k,
                    const float* __restrict__ v,
                    const float* __restrict__ bias_table,
                    float* __restrict__ out)
{
    __shared__ __align__(16) char smem[24464];
    char* sQ = smem + OFF_Q;
    char* sK = smem + OFF_K;
    char* sP = smem + OFF_P;
    char* sV = smem + OFF_V;
    char* sS = smem + OFF_S;
    float* sB = (float*)(smem + OFF_B);

    const int blk  = blockIdx.x;            // 0..16383
    const int head = blk & (NHEADS - 1);
    const int win  = (blk >> 4) & 63;
    const int b    = blk >> 10;
    const int wh   = win >> 3;
    const int ww   = win & 7;

    const int lane = threadIdx.x;           // token index of the row this lane stages
    const int ih = lane >> 3, iw = lane & 7;
    const int quad = lane >> 4, lm = lane & 15;

    // ---- Phase 0: stage bias column, Q (scaled, bf16), K (bf16), V^T (bf16) ----
    for (int t = lane; t < 225; t += 64)
        sB[t] = bias_table[t * NHEADS + head];

    const int gh = (wh * WS + ih + SS) & 63;
    const int gw = (ww * WS + iw + SS) & 63;
    const size_t rowbase = (((size_t)b * 64 + gh) * 64 + gw) * 512 + (size_t)head * HD;

    {
        const float scale = 0.17677669529663687f;  // 32^-0.5
        const float4* qrow = (const float4*)(q + rowbase);
        uint4* qd = (uint4*)(sQ + lane * 80);
        #pragma unroll
        for (int t = 0; t < 4; ++t) {
            float4 a = qrow[2 * t], c = qrow[2 * t + 1];
            uint4 w;
            w.x = pk2(a.x * scale, a.y * scale);
            w.y = pk2(a.z * scale, a.w * scale);
            w.z = pk2(c.x * scale, c.y * scale);
            w.w = pk2(c.z * scale, c.w * scale);
            qd[t] = w;
        }
        const float4* krow = (const float4*)(k + rowbase);
        uint4* kd = (uint4*)(sK + lane * 80);
        #pragma unroll
        for (int t = 0; t < 4; ++t) {
            float4 a = krow[2 * t], c = krow[2 * t + 1];
            uint4 w;
            w.x = pk2(a.x, a.y);
            w.y = pk2(a.z, a.w);
            w.z = pk2(c.x, c.y);
            w.w = pk2(c.z, c.w);
            kd[t] = w;
        }
        const float4* vrow = (const float4*)(v + rowbase);
        #pragma unroll
        for (int t = 0; t < 8; ++t) {
            float4 x = vrow[t];
            *(unsigned short*)(sV + (4 * t + 0) * 144 + lane * 2) = f2bf(x.x);
            *(unsigned short*)(sV + (4 * t + 1) * 144 + lane * 2) = f2bf(x.y);
            *(unsigned short*)(sV + (4 * t + 2) * 144 + lane * 2) = f2bf(x.z);
            *(unsigned short*)(sV + (4 * t + 3) * 144 + lane * 2) = f2bf(x.w);
        }
    }
    __syncthreads();

    // ---- Phase 1: S = Q K^T via 16 MFMAs (acc tiles S[16mt..][16nt..]) ----
    bf16x8 qa[4], kb[4];
    #pragma unroll
    for (int mt = 0; mt < 4; ++mt)
        qa[mt] = *(const bf16x8*)(sQ + (16 * mt + lm) * 80 + quad * 16);
    #pragma unroll
    for (int nt = 0; nt < 4; ++nt)
        kb[nt] = *(const bf16x8*)(sK + (16 * nt + lm) * 80 + quad * 16);

    f32x4 Sacc[4][4];
    #pragma unroll
    for (int mt = 0; mt < 4; ++mt)
        #pragma unroll
        for (int nt = 0; nt < 4; ++nt) {
            f32x4 z = {0.f, 0.f, 0.f, 0.f};
            Sacc[mt][nt] = __builtin_amdgcn_mfma_f32_16x16x32_bf16(qa[mt], kb[nt], z, 0, 0, 0);
        }

    // ---- Phase 2: write S^T to LDS as bf16 (4 acc regs = 4 consecutive i) ----
    #pragma unroll
    for (int mt = 0; mt < 4; ++mt)
        #pragma unroll
        for (int nt = 0; nt < 4; ++nt) {
            f32x4 s4 = Sacc[mt][nt];
            uint2 w;
            w.x = pk2(s4[0], s4[1]);
            w.y = pk2(s4[2], s4[3]);
            // St[j = 16nt+lm][i = 16mt+4quad .. +3]
            *(uint2*)(sS + (16 * nt + lm) * 136 + (16 * mt + 4 * quad) * 2) = w;
        }
    __syncthreads();

    // ---- Phase 3: per-lane row softmax (lane = query i), write P bf16 row-major ----
    float p[64];
    float l = 0.f;
    const bool eh = (wh == 7), ew = (ww == 7);
    const bool aH = (ih < 4), aW = (iw < 4);
    const char* bb = (const char*)sB + 4 * (ih * 15 + iw);
    const char* sc = sS + lane * 2;
    #pragma unroll
    for (int j = 0; j < 64; ++j) {
        const int jh = j >> 3, jw = j & 7;
        float s = bf2f(*(const unsigned short*)(sc + j * 136));
        s += *(const float*)(bb + 4 * ((7 - jh) * 15 + (7 - jw)));
        bool ok = (!eh || (aH == (jh < 4))) && (!ew || (aW == (jw < 4)));
        float e = ok ? __expf(s) : 0.f;   // masked entries: exp(s-100) ~ 0
        p[j] = e;
        l += e;
    }
    const float rl = 1.f / l;
    {
        uint4* pd = (uint4*)(sP + lane * 144);
        #pragma unroll
        for (int t = 0; t < 8; ++t) {
            uint4 w;
            w.x = pk2(p[8 * t + 0] * rl, p[8 * t + 1] * rl);
            w.y = pk2(p[8 * t + 2] * rl, p[8 * t + 3] * rl);
            w.z = pk2(p[8 * t + 4] * rl, p[8 * t + 5] * rl);
            w.w = pk2(p[8 * t + 6] * rl, p[8 * t + 7] * rl);
            pd[t] = w;
        }
    }
    __syncthreads();

    // ---- Phase 4: O = P V via 16 MFMAs ----
    bf16x8 pa[4][2], vb[2][2];
    #pragma unroll
    for (int mt = 0; mt < 4; ++mt)
        #pragma unroll
        for (int ks = 0; ks < 2; ++ks)
            pa[mt][ks] = *(const bf16x8*)(sP + (16 * mt + lm) * 144 + ks * 64 + quad * 16);
    #pragma unroll
    for (int nt = 0; nt < 2; ++nt)
        #pragma unroll
        for (int ks = 0; ks < 2; ++ks)
            vb[nt][ks] = *(const bf16x8*)(sV + (16 * nt + lm) * 144 + ks * 64 + quad * 16);

    f32x4 O[4][2];
    #pragma unroll
    for (int mt = 0; mt < 4; ++mt)
        #pragma unroll
        for (int nt = 0; nt < 2; ++nt) {
            f32x4 z = {0.f, 0.f, 0.f, 0.f};
            z = __builtin_amdgcn_mfma_f32_16x16x32_bf16(pa[mt][0], vb[nt][0], z, 0, 0, 0);
            O[mt][nt] = __builtin_amdgcn_mfma_f32_16x16x32_bf16(pa[mt][1], vb[nt][1], z, 0, 0, 0);
        }

    // ---- Phase 5: store O (C-layout: row i = 16mt+4quad+r, col = 16nt+lm) ----
    #pragma unroll
    for (int mt = 0; mt < 4; ++mt)
        #pragma unroll
        for (int r = 0; r < 4; ++r) {
            const int i = 16 * mt + 4 * quad + r;
            const int ghh = (wh * WS + (i >> 3) + SS) & 63;
            const int gww = (ww * WS + (i & 7) + SS) & 63;
            float* rp = out + (((size_t)b * 64 + ghh) * 64 + gww) * 512 + (size_t)head * HD + lm;
            rp[0]  = O[mt][0][r];
            rp[16] = O[mt][1][r];
        }
}

extern "C" void kernel_launch(void* const* d_in, const int* in_sizes, int n_in,
                              void* d_out, int out_size, void* d_ws, size_t ws_size,
                              hipStream_t stream) {
    const float* q  = (const float*)d_in[0];
    const float* k  = (const float*)d_in[1];
    const float* v  = (const float*)d_in[2];
    const float* bt = (const float*)d_in[3];
    float* out = (float*)d_out;

    dim3 grid(TB * 64 * NHEADS);   // 16384 (window,head) problems, 1 wave each
    dim3 block(64);
    swin_attn_mfma<<<grid, block, 0, stream>>>(q, k, v, bt, out);
}